// Round 8
// baseline (187.852 us; speedup 1.0000x reference)
//
#include <hip/hip_runtime.h>
#include <hip/hip_bf16.h>
#include <stdint.h>

typedef __attribute__((ext_vector_type(8))) short bf16x8;
typedef __attribute__((ext_vector_type(4))) short bf16x4;
typedef __attribute__((ext_vector_type(4))) float f32x4;

#define T_SEQ   8192
#define D_HEAD  64
#define NHEADS  16          // B*H
#define WIN     512
#define BQ      128
#define BK      64
#define NTILES  (T_SEQ / BK)
#define TILE_E  (BK * D_HEAD)   // 4096 bf16 = 8 KB
#define LDSR    72          // (fallback kernel only) padded LDS row stride
#define MASKVAL (-1.0e6f)

#define WS_NEEDED ((size_t)2 * NHEADS * T_SEQ * D_HEAD * 2)   // Kb + Vt, bf16

// 16x16x16 bf16 MFMA (K=16): B-operand layout (k=quad*4+j, n=lane&15) == S^T C-layout,
// so exp'd scores feed PV directly from registers (no LDS P round-trip).
#define MFMA16(a,b,c) __builtin_amdgcn_mfma_f32_16x16x16bf16_1k(a,b,c,0,0,0)

// Single v_exp_f32 (verified r2/r3: same absmax, VALUBusy 53.5->38).
extern "C" __device__ __attribute__((const)) float __ocml_native_exp2_f32(float);
__device__ __forceinline__ float fexp2(float x) { return __ocml_native_exp2_f32(x); }

// HBM -> LDS DMA, 16B per lane, no VGPR staging (register-free: avoids the R5 spill).
// LDS dest is wave-uniform base + lane*16 (linear); swizzle lives in the HBM layout.
#define GLDS16(g, l) __builtin_amdgcn_global_load_lds( \
    (const __attribute__((address_space(1))) void*)(g), \
    (__attribute__((address_space(3))) void*)(l), 16, 0, 0)

__device__ __forceinline__ short f2bf(float f) {
    union { float f; uint32_t u; } v; v.f = f;
    return (short)((v.u + 0x7FFFu + ((v.u >> 16) & 1u)) >> 16);   // RNE, finite inputs
}

__device__ __forceinline__ uint32_t pkbf2(float lo, float hi) {
    union { __hip_bfloat162 h; uint32_t u; } c;
    c.h = __float22bfloat162_rn(make_float2(lo, hi));             // v_cvt_pk_bf16_f32
    return c.u;
}

// ---------------- prep: K -> bf16 chunk-swizzled, V -> bf16 transposed pair-packed ----------------
// (verified R7: absmax unchanged, LDS bank conflicts -> 0)
// K: 16B chunk c of row r stored at slot (c ^ (r&7)) (both-sides swizzle, LDS stays linear).
// V (transposed, [d][key]): chunk c = h*4+q holds keys {h*32+q*4+0..3, h*32+16+q*4+0..3};
// one b128 read gives a lane BOTH kt=2h and kt=2h+1 fragments. Chunk slot = c^(d&7).
__global__ __launch_bounds__(256, 2)
void prep_kv(const float* __restrict__ Kg, const float* __restrict__ Vg,
             short* __restrict__ Kb, short* __restrict__ Vt)
{
    __shared__ float vt[64 * 65];
    const int tid  = threadIdx.x;
    const int tile = blockIdx.x & (NTILES - 1);
    const int head = blockIdx.x >> 7;           // NTILES = 128
    const size_t off = ((size_t)head * T_SEQ + (size_t)tile * BK) * D_HEAD;

    const float* ks = Kg + off;
    short* kd = Kb + off;
    #pragma unroll
    for (int i = 0; i < 2; ++i) {
        int L = tid + 256 * i;                  // 0..511
        int row = L >> 3, c = L & 7;
        const float* s = ks + row * 64 + c * 8;
        float4 a = *(const float4*)s;
        float4 b = *(const float4*)(s + 4);
        short out[8] = { f2bf(a.x), f2bf(a.y), f2bf(a.z), f2bf(a.w),
                         f2bf(b.x), f2bf(b.y), f2bf(b.z), f2bf(b.w) };
        *(bf16x8*)(kd + (row * 8 + (c ^ (row & 7))) * 8) = *(bf16x8*)out;
    }

    const float* vs = Vg + off;
    #pragma unroll
    for (int i = 0; i < 4; ++i) {
        int idx = tid + 256 * i;
        int row = idx >> 4, c4 = (idx & 15) << 2;
        float4 v = *(const float4*)(vs + row * D_HEAD + c4);
        *(float4*)&vt[row * 65 + c4] = v;
    }
    __syncthreads();
    short* vd = Vt + ((size_t)head * NTILES + tile) * TILE_E;
    {
        int d = tid >> 2, q = tid & 3;
        #pragma unroll
        for (int h = 0; h < 2; ++h) {
            int c = h * 4 + q;
            short out[8];
            #pragma unroll
            for (int j = 0; j < 4; ++j) out[j]     = f2bf(vt[(h*32      + q*4 + j) * 65 + d]);
            #pragma unroll
            for (int j = 0; j < 4; ++j) out[4 + j] = f2bf(vt[(h*32 + 16 + q*4 + j) * 65 + d]);
            *(bf16x8*)(vd + (d * 8 + (c ^ (d & 7))) * 8) = *(bf16x8*)out;
        }
    }
}

// ---------------- main: 3-buffer DMA pipeline, counted vmcnt(4), raw s_barrier ----------------
__global__ __launch_bounds__(256, 3)
void swa_fwd(const float* __restrict__ Qg, const short* __restrict__ Kb,
             const short* __restrict__ Vt, float* __restrict__ Og)
{
    __shared__ short Ks[3][TILE_E];          // [buf][key][d], linear, chunk-swizzled data
    __shared__ short Vs[3][TILE_E];          // [buf][d][key], linear, pair-packed+swizzled

    const int tid  = threadIdx.x;
    const int wave = tid >> 6;
    const int lane = tid & 63;
    const int lcol = lane & 15;
    const int quad = lane >> 4;
    const int rx   = lcol & 7;               // row&7 for all our swizzled reads

    const int g    = blockIdx.x;
    const int head = g >> 6;                            // 0..15
    const int qt   = ((g & 7) << 3) | ((g >> 3) & 7);   // 0..63 (XCD swizzle)
    const int q0   = qt * BQ;
    const int tq   = q0 >> 6;

    const float* Qp = Qg + (size_t)head * T_SEQ * D_HEAD;
    const short* Kp = Kb + (size_t)head * T_SEQ * D_HEAD;
    float*       Op = Og + (size_t)head * T_SEQ * D_HEAD;

    const float qscale = 0.125f * 1.44269504088896340736f;  // 1/sqrt(D) * log2(e)
    const int qrow_w = q0 + wave * 32;

    // Q fragments first: their vmcnt waits retire here, so in-loop vmcnt counts only DMAs.
    bf16x8 qf[2][2];
    #pragma unroll
    for (int mt = 0; mt < 2; ++mt) {
        const float* qptr = Qp + (size_t)(qrow_w + mt*16 + lcol) * D_HEAD + quad * 8;
        #pragma unroll
        for (int ks = 0; ks < 2; ++ks) {
            float4 a = *(const float4*)(qptr + ks*32);
            float4 b = *(const float4*)(qptr + ks*32 + 4);
            bf16x8 f;
            f[0]=f2bf(a.x*qscale); f[1]=f2bf(a.y*qscale); f[2]=f2bf(a.z*qscale); f[3]=f2bf(a.w*qscale);
            f[4]=f2bf(b.x*qscale); f[5]=f2bf(b.y*qscale); f[6]=f2bf(b.z*qscale); f[7]=f2bf(b.w*qscale);
            qf[mt][ks] = f;
        }
    }

    // O^T accumulators: oacc[mt][nt] rows d = nt*16+quad*4+r, col q = lcol (q-group mt)
    f32x4 oacc[2][4];
    float l_run[2];
    const f32x4 zero4 = {0.f, 0.f, 0.f, 0.f};
    #pragma unroll
    for (int mt = 0; mt < 2; ++mt) {
        l_run[mt] = 0.f;
        #pragma unroll
        for (int nt = 0; nt < 4; ++nt) oacc[mt][nt] = zero4;
    }

    int t0 = (q0 - WIN) >> 6;            if (t0 < 0) t0 = 0;
    int t1 = (q0 + BQ - 1 + WIN) >> 6;   if (t1 > NTILES - 1) t1 = NTILES - 1;

    // DMA chunk ids: tile = 8 KB = 8 wave-chunks of 1024 B; 4 waves x 2 chunks each
    const int ch0 = wave * 2, ch1 = wave * 2 + 1;

    // ---- prologue: DMA t0 -> buf0, t0+1 -> buf1 (8 ops outstanding) ----
    {
        const short* ksrc = Kp + (size_t)t0 * TILE_E;
        const short* vsrc = Vt + ((size_t)head * NTILES + t0) * TILE_E;
        GLDS16(ksrc + ch0*512 + lane*8, &Ks[0][ch0*512]);
        GLDS16(ksrc + ch1*512 + lane*8, &Ks[0][ch1*512]);
        GLDS16(vsrc + ch0*512 + lane*8, &Vs[0][ch0*512]);
        GLDS16(vsrc + ch1*512 + lane*8, &Vs[0][ch1*512]);
    }
    {
        const int tn = (t0 + 1 <= t1) ? t0 + 1 : t1;
        const short* ksrc = Kp + (size_t)tn * TILE_E;
        const short* vsrc = Vt + ((size_t)head * NTILES + tn) * TILE_E;
        GLDS16(ksrc + ch0*512 + lane*8, &Ks[1][ch0*512]);
        GLDS16(ksrc + ch1*512 + lane*8, &Ks[1][ch1*512]);
        GLDS16(vsrc + ch0*512 + lane*8, &Vs[1][ch0*512]);
        GLDS16(vsrc + ch1*512 + lane*8, &Vs[1][ch1*512]);
    }

    int bi = 0;
    for (int t = t0; t <= t1; ++t) {
        // tile t was issued two iterations ago: wait for oldest 4 only (t+1, t+2 stay in flight)
        asm volatile("s_waitcnt vmcnt(4)" ::: "memory");
        __builtin_amdgcn_s_barrier();     // raw: no implicit vmcnt(0) drain (unlike __syncthreads)
        asm volatile("" ::: "memory");

        // ---- issue DMA for tile t+2 into the buffer read at iter t-1 (all waves are
        //      past the barrier => its reads completed). Uniform 4 ops keeps counts exact. ----
        {
            int tn = t + 2; if (tn > t1) tn = t1;
            int bw = bi + 2; if (bw >= 3) bw -= 3;
            const short* ksrc = Kp + (size_t)tn * TILE_E;
            const short* vsrc = Vt + ((size_t)head * NTILES + tn) * TILE_E;
            short* kds = &Ks[bw][0];
            short* vds = &Vs[bw][0];
            GLDS16(ksrc + ch0*512 + lane*8, kds + ch0*512);
            GLDS16(ksrc + ch1*512 + lane*8, kds + ch1*512);
            GLDS16(vsrc + ch0*512 + lane*8, vds + ch0*512);
            GLDS16(vsrc + ch1*512 + lane*8, vds + ch1*512);
        }

        // ---- compute from buf[bi] (R6 body + pair-packed V reads, verified R7) ----
        const short* Kcur = &Ks[bi][0];
        const short* Vcur = &Vs[bi][0];
        const bool edge = (t < tq - 6) || (t > tq + 7);

        #pragma unroll
        for (int h = 0; h < 2; ++h) {            // key halves: kt = 2h, 2h+1
            // one b128 per nt covers BOTH kt=2h (elems 0-3) and kt=2h+1 (elems 4-7)
            bf16x8 vv[4];
            #pragma unroll
            for (int nt = 0; nt < 4; ++nt)
                vv[nt] = *(const bf16x8*)&Vcur[(nt*16 + lcol)*64 + (((h*4 + quad) ^ rx) << 3)];

            f32x4 sc[2][2];
            #pragma unroll
            for (int j = 0; j < 2; ++j) { sc[j][0] = zero4; sc[j][1] = zero4; }
            #pragma unroll
            for (int ks = 0; ks < 2; ++ks) {
                #pragma unroll
                for (int j = 0; j < 2; ++j) {
                    // logical chunk c = ks*4+quad at row (2h+j)*16+lcol -> slot c^rx
                    bf16x8 kf = *(const bf16x8*)&Kcur[((2*h+j)*16 + lcol)*64
                                                      + (((ks*4 + quad) ^ rx) << 3)];
                    sc[j][0] = __builtin_amdgcn_mfma_f32_16x16x32_bf16(kf, qf[0][ks], sc[j][0], 0,0,0);
                    sc[j][1] = __builtin_amdgcn_mfma_f32_16x16x32_bf16(kf, qf[1][ks], sc[j][1], 0,0,0);
                }
            }

            if (edge) {
                #pragma unroll
                for (int j = 0; j < 2; ++j) {
                    const int kg0 = t*BK + (2*h+j)*16 + quad*4;
                    #pragma unroll
                    for (int mt = 0; mt < 2; ++mt) {
                        const int qg = qrow_w + mt*16 + lcol;
                        #pragma unroll
                        for (int r = 0; r < 4; ++r) {
                            int dq = qg - (kg0 + r);
                            if (dq > WIN || dq < -WIN) sc[j][mt][r] = MASKVAL;
                        }
                    }
                }
            }

            #pragma unroll
            for (int j = 0; j < 2; ++j) {
                bf16x4 vh[4];
                #pragma unroll
                for (int nt = 0; nt < 4; ++nt) {
                    bf16x8 v8 = vv[nt];
                    bf16x4 x = { v8[j*4+0], v8[j*4+1], v8[j*4+2], v8[j*4+3] };
                    vh[nt] = x;
                }
                #pragma unroll
                for (int mt = 0; mt < 2; ++mt) {
                    float p0 = fexp2(sc[j][mt][0]);
                    float p1 = fexp2(sc[j][mt][1]);
                    float p2 = fexp2(sc[j][mt][2]);
                    float p3 = fexp2(sc[j][mt][3]);
                    l_run[mt] += (p0 + p1) + (p2 + p3);
                    union { int2 i; bf16x4 v; } pf;
                    pf.i = make_int2((int)pkbf2(p0, p1), (int)pkbf2(p2, p3));
                    #pragma unroll
                    for (int nt = 0; nt < 4; ++nt)
                        oacc[mt][nt] = MFMA16(vh[nt], pf.v, oacc[mt][nt]);
                }
            }
        }

        bi = (bi == 2) ? 0 : bi + 1;
    }

    // drain remaining in-flight DMAs before exit
    asm volatile("s_waitcnt vmcnt(0)" ::: "memory");

    // epilogue: reduce l over quads, O^T -> O[q][d] with contiguous float4 stores
    #pragma unroll
    for (int mt = 0; mt < 2; ++mt) {
        float l = l_run[mt];
        l += __shfl_xor(l, 16, 64);
        l += __shfl_xor(l, 32, 64);
        float inv = 1.0f / l;
        const int qg = qrow_w + mt*16 + lcol;
        float* op = Op + (size_t)qg * D_HEAD + quad*4;
        #pragma unroll
        for (int nt = 0; nt < 4; ++nt) {
            float4 o = { oacc[mt][nt][0]*inv, oacc[mt][nt][1]*inv,
                         oacc[mt][nt][2]*inv, oacc[mt][nt][3]*inv };
            *(float4*)(op + nt*16) = o;
        }
    }
}

// ---------------- fallback (ws too small): fused 3-barrier kernel, verified round 2 ----------------
#define BQF     128
__global__ __launch_bounds__(256, 4)
void swa_fused_fb(const float* __restrict__ Qg, const float* __restrict__ Kg,
                  const float* __restrict__ Vg, float* __restrict__ Og)
{
    __shared__ short Ksf[BK * LDSR];
    __shared__ short Vsf[D_HEAD * LDSR];
    __shared__ float Vtmp[BK * 65];

    const int tid  = threadIdx.x;
    const int wave = tid >> 6;
    const int lane = tid & 63;
    const int lcol = lane & 15;
    const int quad = lane >> 4;

    const int g    = blockIdx.x;
    const int head = g >> 6;
    const int qt   = ((g & 7) << 3) | ((g >> 3) & 7);
    const int q0   = qt * BQF;
    const int tq   = q0 >> 6;

    const size_t hoff = (size_t)head * T_SEQ * D_HEAD;
    const float* Qp = Qg + hoff;
    const float* Kp = Kg + hoff;
    const float* Vp = Vg + hoff;
    float*       Op = Og + hoff;

    const float qscale = 0.125f * 1.44269504088896340736f;
    const int qrow_w = q0 + wave * 32;

    bf16x8 qf[2][2];
    #pragma unroll
    for (int mt = 0; mt < 2; ++mt) {
        const float* qptr = Qp + (size_t)(qrow_w + mt*16 + lcol) * D_HEAD + quad * 8;
        #pragma unroll
        for (int ks = 0; ks < 2; ++ks) {
            float4 a = *(const float4*)(qptr + ks*32);
            float4 b = *(const float4*)(qptr + ks*32 + 4);
            bf16x8 f;
            f[0]=f2bf(a.x*qscale); f[1]=f2bf(a.y*qscale); f[2]=f2bf(a.z*qscale); f[3]=f2bf(a.w*qscale);
            f[4]=f2bf(b.x*qscale); f[5]=f2bf(b.y*qscale); f[6]=f2bf(b.z*qscale); f[7]=f2bf(b.w*qscale);
            qf[mt][ks] = f;
        }
    }

    f32x4 oacc[2][4];
    float l_run[2];
    const f32x4 zero4 = {0.f, 0.f, 0.f, 0.f};
    #pragma unroll
    for (int mt = 0; mt < 2; ++mt) {
        l_run[mt] = 0.f;
        #pragma unroll
        for (int nt = 0; nt < 4; ++nt) oacc[mt][nt] = zero4;
    }

    int t0 = (q0 - WIN) >> 6;            if (t0 < 0) t0 = 0;
    int t1 = (q0 + BQF - 1 + WIN) >> 6;  if (t1 > NTILES - 1) t1 = NTILES - 1;

    const int krow0 = tid >> 3, kc = (tid & 7) << 3;
    const int krow1 = krow0 + 32;
    const int vrow  = tid >> 4, vc = (tid & 15) << 2;
    const int td    = tid >> 2, tkq = (tid & 3) << 4;

    for (int t = t0; t <= t1; ++t) {
        const float* ksrc = Kp + (size_t)t * BK * D_HEAD;
        const float* vsrc = Vp + (size_t)t * BK * D_HEAD;
        float4 k00 = *(const float4*)(ksrc + krow0*D_HEAD + kc);
        float4 k01 = *(const float4*)(ksrc + krow0*D_HEAD + kc + 4);
        float4 k10 = *(const float4*)(ksrc + krow1*D_HEAD + kc);
        float4 k11 = *(const float4*)(ksrc + krow1*D_HEAD + kc + 4);
        float4 v0  = *(const float4*)(vsrc + (vrow     )*D_HEAD + vc);
        float4 v1  = *(const float4*)(vsrc + (vrow + 16)*D_HEAD + vc);
        float4 v2  = *(const float4*)(vsrc + (vrow + 32)*D_HEAD + vc);
        float4 v3  = *(const float4*)(vsrc + (vrow + 48)*D_HEAD + vc);

        __syncthreads();

        *(float4*)&Vtmp[(vrow     )*65 + vc] = v0;
        *(float4*)&Vtmp[(vrow + 16)*65 + vc] = v1;
        *(float4*)&Vtmp[(vrow + 32)*65 + vc] = v2;
        *(float4*)&Vtmp[(vrow + 48)*65 + vc] = v3;
        *(int4*)&Ksf[krow0*LDSR + kc] = make_int4((int)pkbf2(k00.x,k00.y), (int)pkbf2(k00.z,k00.w),
                                                  (int)pkbf2(k01.x,k01.y), (int)pkbf2(k01.z,k01.w));
        *(int4*)&Ksf[krow1*LDSR + kc] = make_int4((int)pkbf2(k10.x,k10.y), (int)pkbf2(k10.z,k10.w),
                                                  (int)pkbf2(k11.x,k11.y), (int)pkbf2(k11.z,k11.w));

        __syncthreads();

        {
            uint32_t w0 = pkbf2(Vtmp[(tkq+ 0)*65 + td], Vtmp[(tkq+ 1)*65 + td]);
            uint32_t w1 = pkbf2(Vtmp[(tkq+ 2)*65 + td], Vtmp[(tkq+ 3)*65 + td]);
            uint32_t w2 = pkbf2(Vtmp[(tkq+ 4)*65 + td], Vtmp[(tkq+ 5)*65 + td]);
            uint32_t w3 = pkbf2(Vtmp[(tkq+ 6)*65 + td], Vtmp[(tkq+ 7)*65 + td]);
            uint32_t w4 = pkbf2(Vtmp[(tkq+ 8)*65 + td], Vtmp[(tkq+ 9)*65 + td]);
            uint32_t w5 = pkbf2(Vtmp[(tkq+10)*65 + td], Vtmp[(tkq+11)*65 + td]);
            uint32_t w6 = pkbf2(Vtmp[(tkq+12)*65 + td], Vtmp[(tkq+13)*65 + td]);
            uint32_t w7 = pkbf2(Vtmp[(tkq+14)*65 + td], Vtmp[(tkq+15)*65 + td]);
            *(int4*)&Vsf[td*LDSR + tkq]     = make_int4((int)w0,(int)w1,(int)w2,(int)w3);
            *(int4*)&Vsf[td*LDSR + tkq + 8] = make_int4((int)w4,(int)w5,(int)w6,(int)w7);
        }

        __syncthreads();

        const bool edge = (t < tq - 6) || (t > tq + 7);

        #pragma unroll
        for (int h = 0; h < 2; ++h) {
            f32x4 sc[2][2];
            #pragma unroll
            for (int j = 0; j < 2; ++j) { sc[j][0] = zero4; sc[j][1] = zero4; }
            #pragma unroll
            for (int ks = 0; ks < 2; ++ks) {
                #pragma unroll
                for (int j = 0; j < 2; ++j) {
                    bf16x8 kf = *(const bf16x8*)&Ksf[((2*h+j)*16 + lcol)*LDSR + ks*32 + quad*8];
                    sc[j][0] = __builtin_amdgcn_mfma_f32_16x16x32_bf16(kf, qf[0][ks], sc[j][0], 0,0,0);
                    sc[j][1] = __builtin_amdgcn_mfma_f32_16x16x32_bf16(kf, qf[1][ks], sc[j][1], 0,0,0);
                }
            }

            if (edge) {
                #pragma unroll
                for (int j = 0; j < 2; ++j) {
                    const int kg0 = t*BK + (2*h+j)*16 + quad*4;
                    #pragma unroll
                    for (int mt = 0; mt < 2; ++mt) {
                        const int qg = qrow_w + mt*16 + lcol;
                        #pragma unroll
                        for (int r = 0; r < 4; ++r) {
                            int dq = qg - (kg0 + r);
                            if (dq > WIN || dq < -WIN) sc[j][mt][r] = MASKVAL;
                        }
                    }
                }
            }

            #pragma unroll
            for (int j = 0; j < 2; ++j) {
                const int kt = 2*h + j;
                bf16x4 vf[4];
                #pragma unroll
                for (int nt = 0; nt < 4; ++nt)
                    vf[nt] = *(const bf16x4*)&Vsf[(nt*16 + lcol)*LDSR + kt*16 + quad*4];
                #pragma unroll
                for (int mt = 0; mt < 2; ++mt) {
                    float p0 = fexp2(sc[j][mt][0]);
                    float p1 = fexp2(sc[j][mt][1]);
                    float p2 = fexp2(sc[j][mt][2]);
                    float p3 = fexp2(sc[j][mt][3]);
                    l_run[mt] += (p0 + p1) + (p2 + p3);
                    union { int2 i; bf16x4 v; } pf;
                    pf.i = make_int2((int)pkbf2(p0, p1), (int)pkbf2(p2, p3));
                    #pragma unroll
                    for (int nt = 0; nt < 4; ++nt)
                        oacc[mt][nt] = MFMA16(vf[nt], pf.v, oacc[mt][nt]);
                }
            }
        }
    }

    #pragma unroll
    for (int mt = 0; mt < 2; ++mt) {
        float l = l_run[mt];
        l += __shfl_xor(l, 16, 64);
        l += __shfl_xor(l, 32, 64);
        float inv = 1.0f / l;
        const int qg = qrow_w + mt*16 + lcol;
        float* op = Op + (size_t)qg * D_HEAD + quad*4;
        #pragma unroll
        for (int nt = 0; nt < 4; ++nt) {
            float4 o = { oacc[mt][nt][0]*inv, oacc[mt][nt][1]*inv,
                         oacc[mt][nt][2]*inv, oacc[mt][nt][3]*inv };
            *(float4*)(op + nt*16) = o;
        }
    }
}

extern "C" void kernel_launch(void* const* d_in, const int* in_sizes, int n_in,
                              void* d_out, int out_size, void* d_ws, size_t ws_size,
                              hipStream_t stream)
{
    const float* Q = (const float*)d_in[0];
    const float* K = (const float*)d_in[1];
    const float* V = (const float*)d_in[2];
    float* O = (float*)d_out;

    if (ws_size >= WS_NEEDED) {
        short* Kb = (short*)d_ws;
        short* Vt = Kb + (size_t)NHEADS * T_SEQ * D_HEAD;
        prep_kv<<<dim3(NHEADS * NTILES), dim3(256), 0, stream>>>(K, V, Kb, Vt);
        swa_fwd<<<dim3(NHEADS * (T_SEQ / BQ)), dim3(256), 0, stream>>>(Q, Kb, Vt, O);
    } else {
        swa_fused_fb<<<dim3(NHEADS * (T_SEQ / BQF)), dim3(256), 0, stream>>>(Q, K, V, O);
    }
}

// Round 9
// 183.821 us; speedup vs baseline: 1.0219x; 1.0219x over previous
//
#include <hip/hip_runtime.h>
#include <hip/hip_bf16.h>
#include <stdint.h>

typedef __attribute__((ext_vector_type(8))) short bf16x8;
typedef __attribute__((ext_vector_type(4))) short bf16x4;
typedef __attribute__((ext_vector_type(4))) float f32x4;

#define T_SEQ   8192
#define D_HEAD  64
#define NHEADS  16          // B*H
#define WIN     512
#define BQ      128
#define BK      64
#define NTILES  (T_SEQ / BK)
#define TILE_E  (BK * D_HEAD)   // 4096 bf16 = 8 KB
#define LDSR    72          // (fallback kernel only) padded LDS row stride
#define MASKVAL (-1.0e6f)

#define WS_NEEDED ((size_t)2 * NHEADS * T_SEQ * D_HEAD * 2)   // Kb + Vt, bf16

// 16x16x16 bf16 MFMA (K=16): B-operand layout (k=quad*4+j, n=lane&15) == S^T C-layout,
// so exp'd scores feed PV directly from registers (no LDS P round-trip).
#define MFMA16(a,b,c) __builtin_amdgcn_mfma_f32_16x16x16bf16_1k(a,b,c,0,0,0)

// Single v_exp_f32 (verified r2/r3: same absmax, VALUBusy 53.5->38).
extern "C" __device__ __attribute__((const)) float __ocml_native_exp2_f32(float);
__device__ __forceinline__ float fexp2(float x) { return __ocml_native_exp2_f32(x); }

// HBM -> LDS DMA, 16B per lane, no VGPR staging (register-free: avoids the R5 spill).
// LDS dest is wave-uniform base + lane*16 (linear); swizzle lives in the HBM layout.
#define GLDS16(g, l) __builtin_amdgcn_global_load_lds( \
    (const __attribute__((address_space(1))) void*)(g), \
    (__attribute__((address_space(3))) void*)(l), 16, 0, 0)

__device__ __forceinline__ short f2bf(float f) {
    union { float f; uint32_t u; } v; v.f = f;
    return (short)((v.u + 0x7FFFu + ((v.u >> 16) & 1u)) >> 16);   // RNE, finite inputs
}

__device__ __forceinline__ uint32_t pkbf2(float lo, float hi) {
    union { __hip_bfloat162 h; uint32_t u; } c;
    c.h = __float22bfloat162_rn(make_float2(lo, hi));             // v_cvt_pk_bf16_f32
    return c.u;
}

// ---------------- prep: K -> bf16 chunk-swizzled, V -> bf16 transposed pair-packed ----------------
// (verified R7/R8: absmax unchanged, LDS bank conflicts -> 0)
// K: 16B chunk c of row r stored at slot (c ^ (r&7)) (both-sides swizzle, LDS stays linear).
// V (transposed, [d][key]): chunk c = h*4+q holds keys {h*32+q*4+0..3, h*32+16+q*4+0..3};
// one b128 read gives a lane BOTH kt=2h and kt=2h+1 fragments. Chunk slot = c^(d&7).
__global__ __launch_bounds__(256, 2)
void prep_kv(const float* __restrict__ Kg, const float* __restrict__ Vg,
             short* __restrict__ Kb, short* __restrict__ Vt)
{
    __shared__ float vt[64 * 65];
    const int tid  = threadIdx.x;
    const int tile = blockIdx.x & (NTILES - 1);
    const int head = blockIdx.x >> 7;           // NTILES = 128
    const size_t off = ((size_t)head * T_SEQ + (size_t)tile * BK) * D_HEAD;

    const float* ks = Kg + off;
    short* kd = Kb + off;
    #pragma unroll
    for (int i = 0; i < 2; ++i) {
        int L = tid + 256 * i;                  // 0..511
        int row = L >> 3, c = L & 7;
        const float* s = ks + row * 64 + c * 8;
        float4 a = *(const float4*)s;
        float4 b = *(const float4*)(s + 4);
        short out[8] = { f2bf(a.x), f2bf(a.y), f2bf(a.z), f2bf(a.w),
                         f2bf(b.x), f2bf(b.y), f2bf(b.z), f2bf(b.w) };
        *(bf16x8*)(kd + (row * 8 + (c ^ (row & 7))) * 8) = *(bf16x8*)out;
    }

    const float* vs = Vg + off;
    #pragma unroll
    for (int i = 0; i < 4; ++i) {
        int idx = tid + 256 * i;
        int row = idx >> 4, c4 = (idx & 15) << 2;
        float4 v = *(const float4*)(vs + row * D_HEAD + c4);
        *(float4*)&vt[row * 65 + c4] = v;
    }
    __syncthreads();
    short* vd = Vt + ((size_t)head * NTILES + tile) * TILE_E;
    {
        int d = tid >> 2, q = tid & 3;
        #pragma unroll
        for (int h = 0; h < 2; ++h) {
            int c = h * 4 + q;
            short out[8];
            #pragma unroll
            for (int j = 0; j < 4; ++j) out[j]     = f2bf(vt[(h*32      + q*4 + j) * 65 + d]);
            #pragma unroll
            for (int j = 0; j < 4; ++j) out[4 + j] = f2bf(vt[(h*32 + 16 + q*4 + j) * 65 + d]);
            *(bf16x8*)(vd + (d * 8 + (c ^ (d & 7))) * 8) = *(bf16x8*)out;
        }
    }
}

// ---------------- main: R6 2-buffer DMA pipeline (best base, 72.5us) + pair-packed V
// ---------------- + matrix-pipe l-sum (VALU adds + epilogue shuffles -> 8 MFMA16/iter)
__global__ __launch_bounds__(256, 4)
void swa_fwd(const float* __restrict__ Qg, const short* __restrict__ Kb,
             const short* __restrict__ Vt, float* __restrict__ Og)
{
    __shared__ short Ks[2][TILE_E];          // [buf][key][d], linear, chunk-swizzled data
    __shared__ short Vs[2][TILE_E];          // [buf][d][key], linear, pair-packed+swizzled

    const int tid  = threadIdx.x;
    const int wave = tid >> 6;
    const int lane = tid & 63;
    const int lcol = lane & 15;
    const int quad = lane >> 4;
    const int rx   = lcol & 7;               // row&7 for all our swizzled reads

    const int g    = blockIdx.x;
    const int head = g >> 6;                            // 0..15
    const int qt   = ((g & 7) << 3) | ((g >> 3) & 7);   // 0..63 (XCD swizzle)
    const int q0   = qt * BQ;
    const int tq   = q0 >> 6;

    const float* Qp = Qg + (size_t)head * T_SEQ * D_HEAD;
    const short* Kp = Kb + (size_t)head * T_SEQ * D_HEAD;
    float*       Op = Og + (size_t)head * T_SEQ * D_HEAD;

    const float qscale = 0.125f * 1.44269504088896340736f;  // 1/sqrt(D) * log2(e)
    const int qrow_w = q0 + wave * 32;

    // Q fragments first (f2bf forces their vmem waits to retire in the preamble).
    bf16x8 qf[2][2];
    #pragma unroll
    for (int mt = 0; mt < 2; ++mt) {
        const float* qptr = Qp + (size_t)(qrow_w + mt*16 + lcol) * D_HEAD + quad * 8;
        #pragma unroll
        for (int ks = 0; ks < 2; ++ks) {
            float4 a = *(const float4*)(qptr + ks*32);
            float4 b = *(const float4*)(qptr + ks*32 + 4);
            bf16x8 f;
            f[0]=f2bf(a.x*qscale); f[1]=f2bf(a.y*qscale); f[2]=f2bf(a.z*qscale); f[3]=f2bf(a.w*qscale);
            f[4]=f2bf(b.x*qscale); f[5]=f2bf(b.y*qscale); f[6]=f2bf(b.z*qscale); f[7]=f2bf(b.w*qscale);
            qf[mt][ks] = f;
        }
    }

    // O^T accumulators: oacc[mt][nt] rows d = nt*16+quad*4+r, col q = lcol (q-group mt).
    // lacc[mt]: A=ones MFMA16 accumulates sum_k P[k][q] in the matrix pipe (all rows equal),
    // replacing 32 VALU adds/iter and the epilogue cross-quad shuffle reduce.
    f32x4 oacc[2][4];
    f32x4 lacc[2];
    const f32x4 zero4 = {0.f, 0.f, 0.f, 0.f};
    const short oneb = (short)0x3F80;                 // bf16 1.0
    const bf16x4 ones4 = {oneb, oneb, oneb, oneb};
    #pragma unroll
    for (int mt = 0; mt < 2; ++mt) {
        lacc[mt] = zero4;
        #pragma unroll
        for (int nt = 0; nt < 4; ++nt) oacc[mt][nt] = zero4;
    }

    int t0 = (q0 - WIN) >> 6;            if (t0 < 0) t0 = 0;
    int t1 = (q0 + BQ - 1 + WIN) >> 6;   if (t1 > NTILES - 1) t1 = NTILES - 1;

    // DMA chunk ids: tile = 8 KB = 8 wave-chunks of 1024 B; 4 waves x 2 chunks each
    const int ch0 = wave * 2, ch1 = wave * 2 + 1;

    // ---- prologue: DMA tile t0 -> buf0 ----
    {
        const short* ksrc = Kp + (size_t)t0 * TILE_E;
        const short* vsrc = Vt + ((size_t)head * NTILES + t0) * TILE_E;
        GLDS16(ksrc + ch0*512 + lane*8, &Ks[0][ch0*512]);
        GLDS16(ksrc + ch1*512 + lane*8, &Ks[0][ch1*512]);
        GLDS16(vsrc + ch0*512 + lane*8, &Vs[0][ch0*512]);
        GLDS16(vsrc + ch1*512 + lane*8, &Vs[0][ch1*512]);
    }
    asm volatile("s_waitcnt vmcnt(0)" ::: "memory");
    __syncthreads();   // buf0 ready

    int p = 0;
    for (int t = t0; t <= t1; ++t) {
        // ---- issue DMA for tile t+1 into buf[p^1] (register-free; buf[p^1]'s reads
        //      finished at the previous iteration's barrier) ----
        {
            const int tn = (t + 1 <= t1) ? t + 1 : t1;
            const short* ksrc = Kp + (size_t)tn * TILE_E;
            const short* vsrc = Vt + ((size_t)head * NTILES + tn) * TILE_E;
            short* kds = &Ks[p^1][0];
            short* vds = &Vs[p^1][0];
            GLDS16(ksrc + ch0*512 + lane*8, kds + ch0*512);
            GLDS16(ksrc + ch1*512 + lane*8, kds + ch1*512);
            GLDS16(vsrc + ch0*512 + lane*8, vds + ch0*512);
            GLDS16(vsrc + ch1*512 + lane*8, vds + ch1*512);
        }

        // ---- compute from buf[p] ----
        const short* Kcur = &Ks[p][0];
        const short* Vcur = &Vs[p][0];
        const bool edge = (t < tq - 6) || (t > tq + 7);

        #pragma unroll
        for (int h = 0; h < 2; ++h) {            // key halves: kt = 2h, 2h+1
            // one b128 per nt covers BOTH kt=2h (elems 0-3) and kt=2h+1 (elems 4-7)
            bf16x8 vv[4];
            #pragma unroll
            for (int nt = 0; nt < 4; ++nt)
                vv[nt] = *(const bf16x8*)&Vcur[(nt*16 + lcol)*64 + (((h*4 + quad) ^ rx) << 3)];

            f32x4 sc[2][2];
            #pragma unroll
            for (int j = 0; j < 2; ++j) { sc[j][0] = zero4; sc[j][1] = zero4; }
            #pragma unroll
            for (int ks = 0; ks < 2; ++ks) {
                #pragma unroll
                for (int j = 0; j < 2; ++j) {
                    // logical chunk c = ks*4+quad at row (2h+j)*16+lcol -> slot c^rx
                    bf16x8 kf = *(const bf16x8*)&Kcur[((2*h+j)*16 + lcol)*64
                                                      + (((ks*4 + quad) ^ rx) << 3)];
                    sc[j][0] = __builtin_amdgcn_mfma_f32_16x16x32_bf16(kf, qf[0][ks], sc[j][0], 0,0,0);
                    sc[j][1] = __builtin_amdgcn_mfma_f32_16x16x32_bf16(kf, qf[1][ks], sc[j][1], 0,0,0);
                }
            }

            if (edge) {
                #pragma unroll
                for (int j = 0; j < 2; ++j) {
                    const int kg0 = t*BK + (2*h+j)*16 + quad*4;
                    #pragma unroll
                    for (int mt = 0; mt < 2; ++mt) {
                        const int qg = qrow_w + mt*16 + lcol;
                        #pragma unroll
                        for (int r = 0; r < 4; ++r) {
                            int dq = qg - (kg0 + r);
                            if (dq > WIN || dq < -WIN) sc[j][mt][r] = MASKVAL;
                        }
                    }
                }
            }

            #pragma unroll
            for (int j = 0; j < 2; ++j) {
                bf16x4 vh[4];
                #pragma unroll
                for (int nt = 0; nt < 4; ++nt) {
                    bf16x8 v8 = vv[nt];
                    bf16x4 x = { v8[j*4+0], v8[j*4+1], v8[j*4+2], v8[j*4+3] };
                    vh[nt] = x;
                }
                #pragma unroll
                for (int mt = 0; mt < 2; ++mt) {
                    float p0 = fexp2(sc[j][mt][0]);
                    float p1 = fexp2(sc[j][mt][1]);
                    float p2 = fexp2(sc[j][mt][2]);
                    float p3 = fexp2(sc[j][mt][3]);
                    union { int2 i; bf16x4 v; } pf;
                    pf.i = make_int2((int)pkbf2(p0, p1), (int)pkbf2(p2, p3));
                    lacc[mt] = MFMA16(ones4, pf.v, lacc[mt]);     // l += sum_k P[k][q]
                    #pragma unroll
                    for (int nt = 0; nt < 4; ++nt)
                        oacc[mt][nt] = MFMA16(vh[nt], pf.v, oacc[mt][nt]);
                }
            }
        }

        // DMA for t+1 had the whole compute to land; drain + barrier (R6 structure:
        // R8 proved the counted-vmcnt variant buys nothing once occupancy is equal)
        asm volatile("s_waitcnt vmcnt(0)" ::: "memory");
        __syncthreads();
        p ^= 1;
    }

    // epilogue: l from lacc (k-sum spans all quads -> no shuffles), contiguous float4 stores
    #pragma unroll
    for (int mt = 0; mt < 2; ++mt) {
        float inv = 1.0f / lacc[mt][0];
        const int qg = qrow_w + mt*16 + lcol;
        float* op = Op + (size_t)qg * D_HEAD + quad*4;
        #pragma unroll
        for (int nt = 0; nt < 4; ++nt) {
            float4 o = { oacc[mt][nt][0]*inv, oacc[mt][nt][1]*inv,
                         oacc[mt][nt][2]*inv, oacc[mt][nt][3]*inv };
            *(float4*)(op + nt*16) = o;
        }
    }
}

// ---------------- fallback (ws too small): fused 3-barrier kernel, verified round 2 ----------------
#define BQF     128
__global__ __launch_bounds__(256, 4)
void swa_fused_fb(const float* __restrict__ Qg, const float* __restrict__ Kg,
                  const float* __restrict__ Vg, float* __restrict__ Og)
{
    __shared__ short Ksf[BK * LDSR];
    __shared__ short Vsf[D_HEAD * LDSR];
    __shared__ float Vtmp[BK * 65];

    const int tid  = threadIdx.x;
    const int wave = tid >> 6;
    const int lane = tid & 63;
    const int lcol = lane & 15;
    const int quad = lane >> 4;

    const int g    = blockIdx.x;
    const int head = g >> 6;
    const int qt   = ((g & 7) << 3) | ((g >> 3) & 7);
    const int q0   = qt * BQF;
    const int tq   = q0 >> 6;

    const size_t hoff = (size_t)head * T_SEQ * D_HEAD;
    const float* Qp = Qg + hoff;
    const float* Kp = Kg + hoff;
    const float* Vp = Vg + hoff;
    float*       Op = Og + hoff;

    const float qscale = 0.125f * 1.44269504088896340736f;
    const int qrow_w = q0 + wave * 32;

    bf16x8 qf[2][2];
    #pragma unroll
    for (int mt = 0; mt < 2; ++mt) {
        const float* qptr = Qp + (size_t)(qrow_w + mt*16 + lcol) * D_HEAD + quad * 8;
        #pragma unroll
        for (int ks = 0; ks < 2; ++ks) {
            float4 a = *(const float4*)(qptr + ks*32);
            float4 b = *(const float4*)(qptr + ks*32 + 4);
            bf16x8 f;
            f[0]=f2bf(a.x*qscale); f[1]=f2bf(a.y*qscale); f[2]=f2bf(a.z*qscale); f[3]=f2bf(a.w*qscale);
            f[4]=f2bf(b.x*qscale); f[5]=f2bf(b.y*qscale); f[6]=f2bf(b.z*qscale); f[7]=f2bf(b.w*qscale);
            qf[mt][ks] = f;
        }
    }

    f32x4 oacc[2][4];
    float l_run[2];
    const f32x4 zero4 = {0.f, 0.f, 0.f, 0.f};
    #pragma unroll
    for (int mt = 0; mt < 2; ++mt) {
        l_run[mt] = 0.f;
        #pragma unroll
        for (int nt = 0; nt < 4; ++nt) oacc[mt][nt] = zero4;
    }

    int t0 = (q0 - WIN) >> 6;            if (t0 < 0) t0 = 0;
    int t1 = (q0 + BQF - 1 + WIN) >> 6;  if (t1 > NTILES - 1) t1 = NTILES - 1;

    const int krow0 = tid >> 3, kc = (tid & 7) << 3;
    const int krow1 = krow0 + 32;
    const int vrow  = tid >> 4, vc = (tid & 15) << 2;
    const int td    = tid >> 2, tkq = (tid & 3) << 4;

    for (int t = t0; t <= t1; ++t) {
        const float* ksrc = Kp + (size_t)t * BK * D_HEAD;
        const float* vsrc = Vp + (size_t)t * BK * D_HEAD;
        float4 k00 = *(const float4*)(ksrc + krow0*D_HEAD + kc);
        float4 k01 = *(const float4*)(ksrc + krow0*D_HEAD + kc + 4);
        float4 k10 = *(const float4*)(ksrc + krow1*D_HEAD + kc);
        float4 k11 = *(const float4*)(ksrc + krow1*D_HEAD + kc + 4);
        float4 v0  = *(const float4*)(vsrc + (vrow     )*D_HEAD + vc);
        float4 v1  = *(const float4*)(vsrc + (vrow + 16)*D_HEAD + vc);
        float4 v2  = *(const float4*)(vsrc + (vrow + 32)*D_HEAD + vc);
        float4 v3  = *(const float4*)(vsrc + (vrow + 48)*D_HEAD + vc);

        __syncthreads();

        *(float4*)&Vtmp[(vrow     )*65 + vc] = v0;
        *(float4*)&Vtmp[(vrow + 16)*65 + vc] = v1;
        *(float4*)&Vtmp[(vrow + 32)*65 + vc] = v2;
        *(float4*)&Vtmp[(vrow + 48)*65 + vc] = v3;
        *(int4*)&Ksf[krow0*LDSR + kc] = make_int4((int)pkbf2(k00.x,k00.y), (int)pkbf2(k00.z,k00.w),
                                                  (int)pkbf2(k01.x,k01.y), (int)pkbf2(k01.z,k01.w));
        *(int4*)&Ksf[krow1*LDSR + kc] = make_int4((int)pkbf2(k10.x,k10.y), (int)pkbf2(k10.z,k10.w),
                                                  (int)pkbf2(k11.x,k11.y), (int)pkbf2(k11.z,k11.w));

        __syncthreads();

        {
            uint32_t w0 = pkbf2(Vtmp[(tkq+ 0)*65 + td], Vtmp[(tkq+ 1)*65 + td]);
            uint32_t w1 = pkbf2(Vtmp[(tkq+ 2)*65 + td], Vtmp[(tkq+ 3)*65 + td]);
            uint32_t w2 = pkbf2(Vtmp[(tkq+ 4)*65 + td], Vtmp[(tkq+ 5)*65 + td]);
            uint32_t w3 = pkbf2(Vtmp[(tkq+ 6)*65 + td], Vtmp[(tkq+ 7)*65 + td]);
            uint32_t w4 = pkbf2(Vtmp[(tkq+ 8)*65 + td], Vtmp[(tkq+ 9)*65 + td]);
            uint32_t w5 = pkbf2(Vtmp[(tkq+10)*65 + td], Vtmp[(tkq+11)*65 + td]);
            uint32_t w6 = pkbf2(Vtmp[(tkq+12)*65 + td], Vtmp[(tkq+13)*65 + td]);
            uint32_t w7 = pkbf2(Vtmp[(tkq+14)*65 + td], Vtmp[(tkq+15)*65 + td]);
            *(int4*)&Vsf[td*LDSR + tkq]     = make_int4((int)w0,(int)w1,(int)w2,(int)w3);
            *(int4*)&Vsf[td*LDSR + tkq + 8] = make_int4((int)w4,(int)w5,(int)w6,(int)w7);
        }

        __syncthreads();

        const bool edge = (t < tq - 6) || (t > tq + 7);

        #pragma unroll
        for (int h = 0; h < 2; ++h) {
            f32x4 sc[2][2];
            #pragma unroll
            for (int j = 0; j < 2; ++j) { sc[j][0] = zero4; sc[j][1] = zero4; }
            #pragma unroll
            for (int ks = 0; ks < 2; ++ks) {
                #pragma unroll
                for (int j = 0; j < 2; ++j) {
                    bf16x8 kf = *(const bf16x8*)&Ksf[((2*h+j)*16 + lcol)*LDSR + ks*32 + quad*8];
                    sc[j][0] = __builtin_amdgcn_mfma_f32_16x16x32_bf16(kf, qf[0][ks], sc[j][0], 0,0,0);
                    sc[j][1] = __builtin_amdgcn_mfma_f32_16x16x32_bf16(kf, qf[1][ks], sc[j][1], 0,0,0);
                }
            }

            if (edge) {
                #pragma unroll
                for (int j = 0; j < 2; ++j) {
                    const int kg0 = t*BK + (2*h+j)*16 + quad*4;
                    #pragma unroll
                    for (int mt = 0; mt < 2; ++mt) {
                        const int qg = qrow_w + mt*16 + lcol;
                        #pragma unroll
                        for (int r = 0; r < 4; ++r) {
                            int dq = qg - (kg0 + r);
                            if (dq > WIN || dq < -WIN) sc[j][mt][r] = MASKVAL;
                        }
                    }
                }
            }

            #pragma unroll
            for (int j = 0; j < 2; ++j) {
                const int kt = 2*h + j;
                bf16x4 vf[4];
                #pragma unroll
                for (int nt = 0; nt < 4; ++nt)
                    vf[nt] = *(const bf16x4*)&Vsf[(nt*16 + lcol)*LDSR + kt*16 + quad*4];
                #pragma unroll
                for (int mt = 0; mt < 2; ++mt) {
                    float p0 = fexp2(sc[j][mt][0]);
                    float p1 = fexp2(sc[j][mt][1]);
                    float p2 = fexp2(sc[j][mt][2]);
                    float p3 = fexp2(sc[j][mt][3]);
                    l_run[mt] += (p0 + p1) + (p2 + p3);
                    union { int2 i; bf16x4 v; } pf;
                    pf.i = make_int2((int)pkbf2(p0, p1), (int)pkbf2(p2, p3));
                    #pragma unroll
                    for (int nt = 0; nt < 4; ++nt)
                        oacc[mt][nt] = MFMA16(vf[nt], pf.v, oacc[mt][nt]);
                }
            }
        }
    }

    #pragma unroll
    for (int mt = 0; mt < 2; ++mt) {
        float l = l_run[mt];
        l += __shfl_xor(l, 16, 64);
        l += __shfl_xor(l, 32, 64);
        float inv = 1.0f / l;
        const int qg = qrow_w + mt*16 + lcol;
        float* op = Op + (size_t)qg * D_HEAD + quad*4;
        #pragma unroll
        for (int nt = 0; nt < 4; ++nt) {
            float4 o = { oacc[mt][nt][0]*inv, oacc[mt][nt][1]*inv,
                         oacc[mt][nt][2]*inv, oacc[mt][nt][3]*inv };
            *(float4*)(op + nt*16) = o;
        }
    }
}

extern "C" void kernel_launch(void* const* d_in, const int* in_sizes, int n_in,
                              void* d_out, int out_size, void* d_ws, size_t ws_size,
                              hipStream_t stream)
{
    const float* Q = (const float*)d_in[0];
    const float* K = (const float*)d_in[1];
    const float* V = (const float*)d_in[2];
    float* O = (float*)d_out;

    if (ws_size >= WS_NEEDED) {
        short* Kb = (short*)d_ws;
        short* Vt = Kb + (size_t)NHEADS * T_SEQ * D_HEAD;
        prep_kv<<<dim3(NHEADS * NTILES), dim3(256), 0, stream>>>(K, V, Kb, Vt);
        swa_fwd<<<dim3(NHEADS * (T_SEQ / BQ)), dim3(256), 0, stream>>>(Q, Kb, Vt, O);
    } else {
        swa_fused_fb<<<dim3(NHEADS * (T_SEQ / BQF)), dim3(256), 0, stream>>>(Q, K, V, O);
    }
}